// Round 4
// baseline (132.302 us; speedup 1.0000x reference)
//
#include <hip/hip_runtime.h>

// Problem constants (fixed by setup_inputs): seg (1,1,2160,3840) int32, S=512.
#define HH 2160
#define WW 3840
#define SS 512
#define NW (SS * SS / 32)   // 8192 u32 words in the adjacency bitmask
#define NB 512              // seg_main block count (nb >= 256 required by bit-packing)

typedef unsigned int uint;
typedef unsigned long long ull;

// ---------------------------------------------------------------------------
// Main pass. Block b owns a CONTIGUOUS slab of int4-chunks (~4.2 rows), so:
//   - down-row reads are L1/L2-local (same block loads that row as "current")
//   - per-block y - y0 <= 5  ->  centers pack into ONE u64 LDS atomic/pixel:
//       pk = [cnt:16 bits | sum_x:28 bits | sum_y_rel:20 bits]
//     worst case (all 16200 slab pixels in one segment):
//       cnt <= 16200 < 2^16,  sx <= 16200*3839 = 62.2M < 2^28,
//       sy_rel <= 16200*5 = 81000 < 2^20   -> no cross-field carry. (nb=256
//       fallback: 32400 | 124M | 32400*9=291600 -- still fits.)
//   - adjacency: LDS bitmask (bit s*512+n for right/down neighbor n != s),
//     flushed with global atomicOr into the single pre-zeroed wsOr (32 KB,
//     L2-resident; measured round2-vs-round3: cheaper than 32MB staging).
// part layout: uint part[3][SS][nb]  (plane 0=cnt, 1=sum_x, 2=sum_y absolute)
// ---------------------------------------------------------------------------
__global__ __launch_bounds__(512) void seg_main(
    const int* __restrict__ seg, uint* __restrict__ wsOr,
    uint* __restrict__ part, int nb) {
  __shared__ uint s_bm[NW];      // 32 KB adjacency bitmask
  __shared__ ull  s_pk[SS];      // packed cnt|sx|sy_rel
  for (int i = threadIdx.x; i < NW; i += 512) s_bm[i] = 0u;
  for (int i = threadIdx.x; i < SS; i += 512) s_pk[i] = 0ULL;
  __syncthreads();

  const int NC  = HH * WW / 4;               // 2,073,600 int4 chunks
  const int cpb = (NC + nb - 1) / nb;        // 4050 at nb=512
  const int c0  = blockIdx.x * cpb;
  const int c1  = min(c0 + cpb, NC);
  const int y0  = (c0 * 4) / WW;             // slab base row
  const int lane = threadIdx.x & 63;

  const int4* __restrict__ seg4  = (const int4*)seg;
  const int4* __restrict__ seg4d = (const int4*)(seg + WW);  // same idx -> next row

  for (int c = c0 + threadIdx.x; c < c1; c += 512) {
    const int p = c * 4;
    const int y = p / WW;
    const int x = p - y * WW;
    const int4 v = seg4[c];
    // down neighbors (clamped at last row -> self -> no edge)
    const int4 d = (y < HH - 1) ? seg4d[c] : v;
    // right neighbor of element 3: usually next chunk's .x via shuffle from
    // lane+1 (saves a VMEM issue); lane 63 / block-tail load it; row-end -> v.w
    const int nshfl = __shfl_down(v.x, 1, 64);
    const bool need_load = (lane == 63) || (c + 1 >= c1);
    const int  a4 = min(p + 4, HH * WW - 1);           // clamp (speculation-safe)
    const int  nxt = (x >= WW - 4) ? v.w : (need_load ? seg[a4] : nshfl);

    // adjacency bits; s != n only, so the diagonal is never set
    if (v.x != v.y) { int i = v.x * SS + v.y; atomicOr(&s_bm[i >> 5], 1u << (i & 31)); }
    if (v.y != v.z) { int i = v.y * SS + v.z; atomicOr(&s_bm[i >> 5], 1u << (i & 31)); }
    if (v.z != v.w) { int i = v.z * SS + v.w; atomicOr(&s_bm[i >> 5], 1u << (i & 31)); }
    if (v.w != nxt) { int i = v.w * SS + nxt; atomicOr(&s_bm[i >> 5], 1u << (i & 31)); }
    if (v.x != d.x) { int i = v.x * SS + d.x; atomicOr(&s_bm[i >> 5], 1u << (i & 31)); }
    if (v.y != d.y) { int i = v.y * SS + d.y; atomicOr(&s_bm[i >> 5], 1u << (i & 31)); }
    if (v.z != d.z) { int i = v.z * SS + d.z; atomicOr(&s_bm[i >> 5], 1u << (i & 31)); }
    if (v.w != d.w) { int i = v.w * SS + d.w; atomicOr(&s_bm[i >> 5], 1u << (i & 31)); }

    // centers: ONE packed LDS atomic per pixel
    const ull yp = (1ULL << 48) | ((ull)(uint)x << 20) | (ull)(uint)(y - y0);
    atomicAdd(&s_pk[v.x], yp);
    atomicAdd(&s_pk[v.y], yp + (1ULL << 20));
    atomicAdd(&s_pk[v.z], yp + (2ULL << 20));
    atomicAdd(&s_pk[v.w], yp + (3ULL << 20));
  }
  __syncthreads();

  // flush adjacency: global atomicOr into the shared 32 KB mask (~98% nonzero)
  for (int i = threadIdx.x; i < NW; i += 512) {
    const uint m = s_bm[i];
    if (m) atomicOr(&wsOr[i], m);
  }
  // flush center partials (absolute sy = sy_rel + cnt*y0; <= 35M < 2^32)
  for (int i = threadIdx.x; i < SS; i += 512) {
    const ull pk = s_pk[i];
    const uint cnt = (uint)(pk >> 48);
    const uint sx  = (uint)((pk >> 20) & 0x0FFFFFFFu);
    const uint sy  = (uint)(pk & 0xFFFFFu) + cnt * (uint)y0;
    part[(0 * SS + i) * nb + blockIdx.x] = cnt;
    part[(1 * SS + i) * nb + blockIdx.x] = sx;
    part[(2 * SS + i) * nb + blockIdx.x] = sy;
  }
}

// ---------------------------------------------------------------------------
// Fused finalize (wsOr is already fully OR-reduced by the atomics).
// Blocks 0..255:  expand bitmask -> float adjacency, 1 float4 per thread,
//                 8 lanes share a mask word -> coalesced reads and stores.
// Blocks 256..263: centers. 64 segments per block, 4 threads per segment.
// ---------------------------------------------------------------------------
__global__ __launch_bounds__(256) void finalize(
    const uint* __restrict__ wsOr, const uint* __restrict__ part, int nb,
    float* __restrict__ adj, float* __restrict__ centers) {
  const int g = blockIdx.x;
  const int t = threadIdx.x;

  if (g < 256) {                        // ---- adjacency expand ----
    const int q4 = g * 256 + t;         // float4 index (65536 total)
    const uint nib = (wsOr[q4 >> 3] >> ((q4 & 7) * 4)) & 0xFu;
    float4 o;
    o.x = (nib & 1u) ? 1.0f : 0.0f;
    o.y = (nib & 2u) ? 1.0f : 0.0f;
    o.z = (nib & 4u) ? 1.0f : 0.0f;
    o.w = (nib & 8u) ? 1.0f : 0.0f;
    ((float4*)adj)[q4] = o;
  } else {                              // ---- centers reduce ----
    const int s = (g - 256) * 64 + (t >> 2);
    const int q = t & 3;
    ull cnt = 0, sx = 0, sy = 0;
    for (int b = q; b < nb; b += 4) {
      cnt += part[(0 * SS + s) * nb + b];
      sx  += part[(1 * SS + s) * nb + b];
      sy  += part[(2 * SS + s) * nb + b];
    }
    cnt += __shfl_down(cnt, 2, 4); cnt += __shfl_down(cnt, 1, 4);
    sx  += __shfl_down(sx,  2, 4); sx  += __shfl_down(sx,  1, 4);
    sy  += __shfl_down(sy,  2, 4); sy  += __shfl_down(sy,  1, 4);
    if (q == 0) {
      const double dc = (double)cnt;
      centers[s * 2 + 0] = (float)((double)sx / dc);  // W-axis mean first (torch permute)
      centers[s * 2 + 1] = (float)((double)sy / dc);
    }
  }
}

extern "C" void kernel_launch(void* const* d_in, const int* in_sizes, int n_in,
                              void* d_out, int out_size, void* d_ws, size_t ws_size,
                              hipStream_t stream) {
  const int* seg = (const int*)d_in[0];  // (1,1,2160,3840) int32
  float* out = (float*)d_out;
  float* adj = out;                       // 512*512
  float* centers = out + SS * SS;         // 512*2

  uint* wsOr = (uint*)d_ws;               // 8192 words = 32 KB
  uint* part = wsOr + NW;                 // 3*512*nb words (3 MB @ nb=512)

  int nb = NB;
  const size_t need = (size_t)NW * 4 + (size_t)3 * SS * nb * 4;
  if (ws_size < need) {                   // defensive; ws is ~256 MB in practice
    nb = (int)((ws_size - (size_t)NW * 4) / ((size_t)3 * SS * 4));
    if (nb > NB) nb = NB;
    if (nb < 256) nb = 256;               // bit-packing requires nb >= 256
  }

  hipMemsetAsync(wsOr, 0, (size_t)NW * 4, stream);
  seg_main<<<nb, 512, 0, stream>>>(seg, wsOr, part, nb);
  finalize<<<256 + SS / 64, 256, 0, stream>>>(wsOr, part, nb, adj, centers);
}

// Round 5
// 131.895 us; speedup vs baseline: 1.0031x; 1.0031x over previous
//
#include <hip/hip_runtime.h>

// Problem constants (fixed by setup_inputs): seg (1,1,2160,3840) int32, S=512.
#define HH 2160
#define WW 3840
#define SS 512
#define NW (SS * SS / 32)   // 8192 u32 words in the adjacency bitmask
#define NB 512              // seg_main block count

typedef unsigned int uint;
typedef unsigned long long ull;

// ---------------------------------------------------------------------------
// Main pass — BIT-IDENTICAL inner loop to round 2 (the best-measured config:
// grid-stride, direct scalar next-chunk load, 4xu64 + 4xu32 LDS atomics,
// 32 KB global-atomicOr flush). Rounds 3/4 "improvements" (staging; slab +
// packed single atomic + shfl) both regressed: staging added 32 MB of clean
// traffic; the shfl put a dependent ds_bpermute on the contended LDS pipe.
// part layout: uint part[3][SS][nb]  (plane 0=cnt, 1=sum_x, 2=sum_y)
// Overflow: worst case one block sees all its ~16384 pixels in one segment:
//   cnt <= 16384 < 2^24;  sy <= 16384*2159 ~ 3.5e7 < 2^40;  sx <= 6.3e7 < 2^32.
// ---------------------------------------------------------------------------
__global__ __launch_bounds__(512) void seg_main(
    const int* __restrict__ seg, uint* __restrict__ wsOr,
    uint* __restrict__ part, int nb) {
  __shared__ uint s_bm[NW];      // 32 KB adjacency bitmask
  __shared__ ull  s_pk[SS];      // (cnt << 40) | sum_y
  __shared__ uint s_sx[SS];      // sum_x
  for (int i = threadIdx.x; i < NW; i += blockDim.x) s_bm[i] = 0u;
  for (int i = threadIdx.x; i < SS; i += blockDim.x) { s_pk[i] = 0ULL; s_sx[i] = 0u; }
  __syncthreads();

  const int NC = HH * WW / 4;  // int4 chunks; WW % 4 == 0 so chunks never span rows
  const int stride = gridDim.x * blockDim.x;
  const int4* __restrict__ seg4  = (const int4*)seg;
  const int4* __restrict__ seg4d = (const int4*)(seg + WW);  // same idx -> next row

  for (int c = blockIdx.x * blockDim.x + threadIdx.x; c < NC; c += stride) {
    const int p = c * 4;
    const int y = p / WW;
    const int x = p - y * WW;
    const int4 v = seg4[c];
    // down neighbors (clamped at last row -> self -> no edge)
    const int4 d = (y < HH - 1) ? seg4d[c] : v;
    // right neighbor of element 3 (clamped at last column -> self -> no edge)
    const int nxt = (x < WW - 4) ? seg[p + 4] : v.w;

    // adjacency bits; s != n only, so the diagonal is never set
    if (v.x != v.y) { int i = v.x * SS + v.y; atomicOr(&s_bm[i >> 5], 1u << (i & 31)); }
    if (v.y != v.z) { int i = v.y * SS + v.z; atomicOr(&s_bm[i >> 5], 1u << (i & 31)); }
    if (v.z != v.w) { int i = v.z * SS + v.w; atomicOr(&s_bm[i >> 5], 1u << (i & 31)); }
    if (v.w != nxt) { int i = v.w * SS + nxt; atomicOr(&s_bm[i >> 5], 1u << (i & 31)); }
    if (v.x != d.x) { int i = v.x * SS + d.x; atomicOr(&s_bm[i >> 5], 1u << (i & 31)); }
    if (v.y != d.y) { int i = v.y * SS + d.y; atomicOr(&s_bm[i >> 5], 1u << (i & 31)); }
    if (v.z != d.z) { int i = v.z * SS + d.z; atomicOr(&s_bm[i >> 5], 1u << (i & 31)); }
    if (v.w != d.w) { int i = v.w * SS + d.w; atomicOr(&s_bm[i >> 5], 1u << (i & 31)); }

    // centers accumulation: 2 LDS atomics per pixel
    const ull yp = (1ULL << 40) | (ull)(uint)y;
    atomicAdd(&s_pk[v.x], yp); atomicAdd(&s_sx[v.x], (uint)x);
    atomicAdd(&s_pk[v.y], yp); atomicAdd(&s_sx[v.y], (uint)(x + 1));
    atomicAdd(&s_pk[v.z], yp); atomicAdd(&s_sx[v.z], (uint)(x + 2));
    atomicAdd(&s_pk[v.w], yp); atomicAdd(&s_sx[v.w], (uint)(x + 3));
  }
  __syncthreads();

  // flush adjacency bitmask (coalesced global atomicOr; ~98% of words nonzero)
  for (int i = threadIdx.x; i < NW; i += blockDim.x) {
    const uint val = s_bm[i];
    if (val) atomicOr(&wsOr[i], val);
  }
  // flush center partials (transposed layout for coalesced finalize reads)
  for (int i = threadIdx.x; i < SS; i += blockDim.x) {
    const ull pk = s_pk[i];
    part[(0 * SS + i) * nb + blockIdx.x] = (uint)(pk >> 40);
    part[(1 * SS + i) * nb + blockIdx.x] = s_sx[i];
    part[(2 * SS + i) * nb + blockIdx.x] = (uint)(pk & ((1ULL << 40) - 1));
  }
}

// ---------------------------------------------------------------------------
// Fused finalize (wsOr is already fully OR-reduced by the atomics).
// Blocks 0..255:  expand bitmask -> float adjacency, 1 float4 per thread,
//                 8 lanes share a mask word -> coalesced reads and stores.
// Blocks 256..263: centers. 64 segments per block, 4 threads per segment.
// ---------------------------------------------------------------------------
__global__ __launch_bounds__(256) void finalize(
    const uint* __restrict__ wsOr, const uint* __restrict__ part, int nb,
    float* __restrict__ adj, float* __restrict__ centers) {
  const int g = blockIdx.x;
  const int t = threadIdx.x;

  if (g < 256) {                        // ---- adjacency expand ----
    const int q4 = g * 256 + t;         // float4 index (65536 total)
    const uint nib = (wsOr[q4 >> 3] >> ((q4 & 7) * 4)) & 0xFu;
    float4 o;
    o.x = (nib & 1u) ? 1.0f : 0.0f;
    o.y = (nib & 2u) ? 1.0f : 0.0f;
    o.z = (nib & 4u) ? 1.0f : 0.0f;
    o.w = (nib & 8u) ? 1.0f : 0.0f;
    ((float4*)adj)[q4] = o;
  } else {                              // ---- centers reduce ----
    const int s = (g - 256) * 64 + (t >> 2);
    const int q = t & 3;
    ull cnt = 0, sx = 0, sy = 0;
    for (int b = q; b < nb; b += 4) {
      cnt += part[(0 * SS + s) * nb + b];
      sx  += part[(1 * SS + s) * nb + b];
      sy  += part[(2 * SS + s) * nb + b];
    }
    cnt += __shfl_down(cnt, 2, 4); cnt += __shfl_down(cnt, 1, 4);
    sx  += __shfl_down(sx,  2, 4); sx  += __shfl_down(sx,  1, 4);
    sy  += __shfl_down(sy,  2, 4); sy  += __shfl_down(sy,  1, 4);
    if (q == 0) {
      const double dc = (double)cnt;
      centers[s * 2 + 0] = (float)((double)sx / dc);  // W-axis mean first (torch permute)
      centers[s * 2 + 1] = (float)((double)sy / dc);
    }
  }
}

extern "C" void kernel_launch(void* const* d_in, const int* in_sizes, int n_in,
                              void* d_out, int out_size, void* d_ws, size_t ws_size,
                              hipStream_t stream) {
  const int* seg = (const int*)d_in[0];  // (1,1,2160,3840) int32
  float* out = (float*)d_out;
  float* adj = out;                       // 512*512
  float* centers = out + SS * SS;         // 512*2

  uint* wsOr = (uint*)d_ws;               // 8192 words = 32 KB
  uint* part = wsOr + NW;                 // 3*512*nb words (3 MB @ nb=512)

  int nb = NB;
  const size_t need = (size_t)NW * 4 + (size_t)3 * SS * nb * 4;
  if (ws_size < need) {                   // defensive; ws is ~256 MB in practice
    nb = (int)((ws_size - (size_t)NW * 4) / ((size_t)3 * SS * 4));
    if (nb > NB) nb = NB;
    if (nb < 1) nb = 1;
  }

  hipMemsetAsync(wsOr, 0, (size_t)NW * 4, stream);
  seg_main<<<nb, 512, 0, stream>>>(seg, wsOr, part, nb);
  finalize<<<256 + SS / 64, 256, 0, stream>>>(wsOr, part, nb, adj, centers);
}